// Round 1
// baseline (1383.507 us; speedup 1.0000x reference)
//
#include <hip/hip_runtime.h>
#include <hip/hip_bf16.h>
#include <stdint.h>

typedef float v4f __attribute__((ext_vector_type(4)));
typedef short v8s __attribute__((ext_vector_type(8)));
typedef uint16_t u16;

__device__ __forceinline__ void gload_lds16(const void* g, void* l) {
  __builtin_amdgcn_global_load_lds(
      (const __attribute__((address_space(1))) void*)g,
      (__attribute__((address_space(3))) void*)l, 16, 0, 0);
}

// ---------------------------------------------------------------------------
// Fused Hadamard-rotate (FWHT) + MXFP4 quant-dequant -> bf16
// One 32-element group per thread.
// ---------------------------------------------------------------------------
__global__ __launch_bounds__(256) void quant_rot_kernel(
    const float* __restrict__ in, u16* __restrict__ out, int ngroups) {
  int g = blockIdx.x * 256 + threadIdx.x;
  if (g >= ngroups) return;

  float v[32];
  const v4f* p = (const v4f*)(in + (size_t)g * 32);
#pragma unroll
  for (int c = 0; c < 8; ++c) {
    v4f t = p[c];
    v[c * 4 + 0] = t[0];
    v[c * 4 + 1] = t[1];
    v[c * 4 + 2] = t[2];
    v[c * 4 + 3] = t[3];
  }

  // 5-stage FWHT (Sylvester Hadamard; H symmetric so t@H == H*t)
#pragma unroll
  for (int s = 0; s < 5; ++s) {
    const int h = 1 << s;
#pragma unroll
    for (int k = 0; k < 16; ++k) {
      const int i = ((k >> s) << (s + 1)) | (k & (h - 1));
      float a = v[i], b = v[i + h];
      v[i] = a + b;
      v[i + h] = a - b;
    }
  }

  const float RS = 0.17677669529663687f;  // 32^-0.5 (fp32-rounded, matches ref)
  float amax = 0.0f;
#pragma unroll
  for (int i = 0; i < 32; ++i) {
    v[i] *= RS;
    amax = fmaxf(amax, fabsf(v[i]));
  }

  // scale = 2^(floor(log2(max(amax,1e-30))) - 2); exact via exponent bits
  float scale, rscale;
  if (amax > 0.0f) {
    float am = fmaxf(amax, 1e-30f);
    int E = (int)((__float_as_uint(am) >> 23) & 255u) - 127;
    scale  = __uint_as_float((uint32_t)(E - 2 + 127) << 23);
    rscale = __uint_as_float((uint32_t)(2 - E + 127) << 23);
  } else {
    scale = 1.0f;
    rscale = 1.0f;
  }

  u16 o[32];
#pragma unroll
  for (int i = 0; i < 32; ++i) {
    float x = v[i];
    float a = fminf(fabsf(x) * rscale, 6.0f);   // rscale is exact pow2
    // e2m1 binade: step 0.5 for a<2, 1 for [2,4), 2 for [4,6]
    float rstep = a >= 4.0f ? 0.5f : (a >= 2.0f ? 1.0f : 2.0f);
    float step  = a >= 4.0f ? 2.0f : (a >= 2.0f ? 1.0f : 0.5f);
    float q = rintf(a * rstep) * step;          // RNE, matches jnp.round
    float d = copysignf(q * scale, x);          // exact in fp32 AND bf16
    o[i] = (u16)(__float_as_uint(d) >> 16);     // exact truncation
  }

  uint4* dst = (uint4*)(out + (size_t)g * 32);
  const uint4* src = (const uint4*)o;
#pragma unroll
  for (int c = 0; c < 4; ++c) dst[c] = src[c];
}

// ---------------------------------------------------------------------------
// bf16 GEMM, B^T input: C[m][n] = sum_k A[m][k]*B[n][k] + bias[n]
// m97 structure: 128x128 tile, BK=32, 4 waves (2x2), global_load_lds staging.
// ---------------------------------------------------------------------------
__global__ __launch_bounds__(256) void gemm_bf16_bt(
    const u16* __restrict__ A, const u16* __restrict__ B,
    const float* __restrict__ bias, float* __restrict__ C) {
  const int N = 16384, K = 4096;
  __shared__ u16 As[128 * 32];  // row-major [128 rows][32 k], linear (gload_lds)
  __shared__ u16 Bs[128 * 32];

  const int tid  = threadIdx.x;
  const int lane = tid & 63;
  const int wv   = tid >> 6;      // wave 0..3
  const int wm   = wv >> 1;       // wave row (2)
  const int wn   = wv & 1;        // wave col (2)
  const int mTile = blockIdx.y * 128;
  const int nTile = blockIdx.x * 128;

  v4f acc[4][4] = {};

  // staging: 8 chunks of 1024B per tile; wave wv owns chunks {2wv, 2wv+1}
  const int boff0 = (wv * 2 + 0) * 1024 + lane * 16;
  const int boff1 = (wv * 2 + 1) * 1024 + lane * 16;
  const int r0 = boff0 >> 6, c0 = (boff0 & 63) >> 1;  // 64B per row, bf16 elems
  const int r1 = boff1 >> 6, c1 = (boff1 & 63) >> 1;
  const u16* aSrc0 = A + (size_t)(mTile + r0) * K + c0;
  const u16* aSrc1 = A + (size_t)(mTile + r1) * K + c1;
  const u16* bSrc0 = B + (size_t)(nTile + r0) * K + c0;
  const u16* bSrc1 = B + (size_t)(nTile + r1) * K + c1;
  char* aDst0 = (char*)As + (wv * 2 + 0) * 1024;  // wave-uniform LDS base
  char* aDst1 = (char*)As + (wv * 2 + 1) * 1024;
  char* bDst0 = (char*)Bs + (wv * 2 + 0) * 1024;
  char* bDst1 = (char*)Bs + (wv * 2 + 1) * 1024;

  const int ar = wm * 64 + (lane & 15);
  const int br = wn * 64 + (lane & 15);
  const int kk = (lane >> 4) * 8;

  for (int k0 = 0; k0 < K; k0 += 32) {
    gload_lds16(aSrc0, aDst0);
    gload_lds16(aSrc1, aDst1);
    gload_lds16(bSrc0, bDst0);
    gload_lds16(bSrc1, bDst1);
    aSrc0 += 32; aSrc1 += 32; bSrc0 += 32; bSrc1 += 32;
    __syncthreads();  // compiler drains vmcnt before barrier

    v8s af[4], bf[4];
#pragma unroll
    for (int i = 0; i < 4; ++i)
      af[i] = *(const v8s*)&As[(ar + i * 16) * 32 + kk];
#pragma unroll
    for (int j = 0; j < 4; ++j)
      bf[j] = *(const v8s*)&Bs[(br + j * 16) * 32 + kk];

#pragma unroll
    for (int i = 0; i < 4; ++i)
#pragma unroll
      for (int j = 0; j < 4; ++j)
        acc[i][j] = __builtin_amdgcn_mfma_f32_16x16x32_bf16(af[i], bf[j],
                                                            acc[i][j], 0, 0, 0);
    __syncthreads();
  }

  // epilogue: C/D layout col=lane&15, row=(lane>>4)*4+reg (m89-verified)
#pragma unroll
  for (int j = 0; j < 4; ++j) {
    const int col = nTile + wn * 64 + j * 16 + (lane & 15);
    const float bv = bias[col];
#pragma unroll
    for (int i = 0; i < 4; ++i) {
      const int row0 = mTile + wm * 64 + i * 16 + (lane >> 4) * 4;
#pragma unroll
      for (int r = 0; r < 4; ++r)
        C[(size_t)(row0 + r) * N + col] = acc[i][j][r] + bv;
    }
  }
}

// ---------------------------------------------------------------------------
extern "C" void kernel_launch(void* const* d_in, const int* in_sizes, int n_in,
                              void* d_out, int out_size, void* d_ws, size_t ws_size,
                              hipStream_t stream) {
  const float* x    = (const float*)d_in[0];   // 8192 x 4096
  const float* w    = (const float*)d_in[1];   // 16384 x 4096
  const float* bias = (const float*)d_in[2];   // 16384
  // d_in[3] = hadamard(32x32) -- replaced by exact FWHT + 32^-0.5 constant
  float* out = (float*)d_out;                  // 8192 x 16384 fp32

  const int M = 8192, N = 16384, K = 4096;
  u16* x_dq = (u16*)d_ws;                                  // 64 MB
  u16* w_dq = (u16*)((char*)d_ws + (size_t)M * K * 2);     // 128 MB

  const int xg = M * K / 32;   // 1,048,576 groups
  const int wg = N * K / 32;   // 2,097,152 groups
  quant_rot_kernel<<<xg / 256, 256, 0, stream>>>(x, x_dq, xg);
  quant_rot_kernel<<<wg / 256, 256, 0, stream>>>(w, w_dq, wg);

  dim3 grid(N / 128, M / 128);
  gemm_bf16_bt<<<grid, dim3(256), 0, stream>>>(x_dq, w_dq, bias, out);
}